// Round 11
// baseline (390.219 us; speedup 1.0000x reference)
//
#include <hip/hip_runtime.h>
#include <hip/hip_bf16.h>
#include <math.h>

#define NN 50000
#define NE 400000
#define FIN 70
#define EDIM 4
#define HIDD 128
#define NHEAD 4
constexpr int ET = NE + NN;
constexpr int KP1 = 96;           // layer-1 K padded (70 -> 96)
constexpr int NFP = 72;           // nf bf16 row pitch
constexpr int SCB = (NN + 255) / 256;   // scan blocks = 196

constexpr size_t al4(size_t x){ return (x + 3) & ~size_t(3); }
// ws offsets in 4-byte words
constexpr size_t CNT_O   = 0;                          // int[NN] (zeroed each call)
constexpr size_t ZEND    = al4(CNT_O + NN);
constexpr size_t CSR_O   = ZEND;                       // int[NN+1]
constexpr size_t BSUM_O  = al4(CSR_O + NN + 1);        // int[256]
constexpr size_t BOFF_O  = al4(BSUM_O + 256);          // int[256]
constexpr size_t EPK_O   = al4(BOFF_O + 256);          // int4[ET] {s,d,ea01,ea23}
constexpr size_t EXF1_O  = al4(EPK_O + (size_t)ET*4);  // float4[ET] exp scores L1
constexpr size_t EXF2_O  = al4(EXF1_O + (size_t)ET*4); // f32[ET]    exp scores L2
constexpr size_t SS1_O   = al4(EXF2_O + ET);           // f32[NN*4]
constexpr size_t SD1_O   = al4(SS1_O + (size_t)NN*4);
constexpr size_t SS2_O   = al4(SD1_O + (size_t)NN*4);  // f32[NN]
constexpr size_t SD2_O   = al4(SS2_O + NN);
constexpr size_t CST_O   = al4(SD2_O + NN);            // f32[2048]
constexpr size_t W1T_O   = al4(CST_O + 2048);          // bf16[4][128][96]
constexpr size_t W2T_O   = al4(W1T_O + 4*128*KP1/2);   // bf16[128][512]
constexpr size_t NFB_O   = al4(W2T_O + 128*512/2);     // bf16[NN][72]
constexpr size_t AGG_O   = al4(NFB_O + (size_t)NN*NFP/2);   // bf16[4][NN][96]
constexpr size_t XS2_O   = al4(AGG_O + (size_t)4*NN*KP1/2); // bf16[NN][128]

// const-block sub-offsets (words, within CST)
constexpr int VS1 = 0;    // [70][4]
constexpr int VD1 = 320;  // [70][4]
constexpr int VE1 = 640;  // [4][4]
constexpr int VE2 = 656;  // [4]
constexpr int VS2 = 704;  // [512]
constexpr int VD2 = 1216; // [512]

typedef short s8v __attribute__((ext_vector_type(8)));
typedef float f4v __attribute__((ext_vector_type(4)));

__device__ __forceinline__ unsigned short f2b(float v){
  __hip_bfloat16 b = __float2bfloat16(v);
  return *(unsigned short*)&b;
}
__device__ __forceinline__ float b2f(unsigned u_lo16){
  return __uint_as_float(u_lo16 << 16);
}
__device__ __forceinline__ unsigned pk2(float lo, float hi){
  return (unsigned)f2b(lo) | ((unsigned)f2b(hi) << 16);
}
__device__ __forceinline__ float lrelu(float x){ return x > 0.f ? x : 0.2f * x; }

// erf via A&S 7.1.26 (|err|<1.5e-7), one fast v_exp — avoids libm erff
__device__ __forceinline__ float gelu_fast(float x){
  float z = x * 0.70710678118654752440f;
  float a = fabsf(z);
  float t = 1.f / (1.f + 0.3275911f * a);
  float p = ((((1.061405429f*t - 1.453152027f)*t + 1.421413741f)*t
              - 0.284496736f)*t + 0.254829592f)*t;
  float erfv = 1.f - p * __expf(-a * a);
  erfv = copysignf(erfv, z);
  return 0.5f * x * (1.f + erfv);
}

// ---- degree histogram: ONE atomic per edge ----------------------------------
__global__ void k_deg(const int* __restrict__ ei, int* __restrict__ cnt){
  int e = blockIdx.x * 256 + threadIdx.x;
  if (e >= NE) return;
  atomicAdd(&cnt[ei[NE + e]], 1);
}

// ---- CSR build: 3-phase scan of (cnt+1) -------------------------------------
__global__ void k_scan1(const int* __restrict__ cnt, int* __restrict__ bsum){
  __shared__ int ws[4];
  int t = threadIdx.x, lane = t & 63, w = t >> 6;
  int i = blockIdx.x * 256 + t;
  int v = (i < NN) ? cnt[i] + 1 : 0;
  for (int o = 32; o; o >>= 1) v += __shfl_down(v, o);
  if (lane == 0) ws[w] = v;
  __syncthreads();
  if (t == 0) bsum[blockIdx.x] = ws[0] + ws[1] + ws[2] + ws[3];
}

__global__ void k_scan2(const int* __restrict__ bsum, int* __restrict__ boff){
  __shared__ int ws[4];
  int t = threadIdx.x, lane = t & 63, w = t >> 6;
  int v = (t < SCB) ? bsum[t] : 0;
  int x = v;
  #pragma unroll
  for (int o = 1; o < 64; o <<= 1){ int u = __shfl_up(x, o); if (lane >= o) x += u; }
  if (lane == 63) ws[w] = x;
  __syncthreads();
  if (w == 0 && lane < 4){
    int y = ws[lane];
    #pragma unroll
    for (int o = 1; o < 4; o <<= 1){ int u = __shfl_up(y, o); if (lane >= o) y += u; }
    ws[lane] = y;
  }
  __syncthreads();
  int incl = x + (w > 0 ? ws[w - 1] : 0);
  if (t < SCB) boff[t] = incl - v;
}

__global__ void k_scan3(const int* __restrict__ cnt, const int* __restrict__ boff,
                        int* __restrict__ csr){
  __shared__ int ws[4];
  int t = threadIdx.x, lane = t & 63, w = t >> 6;
  int i = blockIdx.x * 256 + t;
  int v = (i < NN) ? cnt[i] + 1 : 0;
  int x = v;
  #pragma unroll
  for (int o = 1; o < 64; o <<= 1){ int u = __shfl_up(x, o); if (lane >= o) x += u; }
  if (lane == 63) ws[w] = x;
  __syncthreads();
  if (w == 0 && lane < 4){
    int y = ws[lane];
    #pragma unroll
    for (int o = 1; o < 4; o <<= 1){ int u = __shfl_up(y, o); if (lane >= o) y += u; }
    ws[lane] = y;
  }
  __syncthreads();
  if (i < NN) csr[i + 1] = boff[blockIdx.x] + (w > 0 ? ws[w - 1] : 0) + x;
  if (i == 0) csr[0] = 0;
}

// ---- fill CSR slots + FUSED layer-1 alpha; consumes cnt -> 0 ----------------
__global__ void k_fill(const int* __restrict__ ei, const float* __restrict__ ea,
                       const int* __restrict__ csr, int* __restrict__ cnt,
                       int4* __restrict__ epk, const float* __restrict__ ss1,
                       const float* __restrict__ sd1, const float* __restrict__ C,
                       float4* __restrict__ exf){
  int e = blockIdx.x * 256 + threadIdx.x;
  if (e >= NE) return;
  int s = ei[e], d = ei[NE + e];
  int r = atomicSub(&cnt[d], 1);        // r in [deg..1]
  int p = csr[d] + r - 1;
  float4 a = *(const float4*)&ea[(size_t)e * 4];
  epk[p] = make_int4(s, d, (int)pk2(a.x, a.y), (int)pk2(a.z, a.w));
  float4 ssv = *(const float4*)&ss1[(size_t)s * 4];
  float4 sdv = *(const float4*)&sd1[(size_t)d * 4];
  float e0 = __expf(lrelu(ssv.x + sdv.x + a.x*C[VE1+0] + a.y*C[VE1+4] + a.z*C[VE1+8]  + a.w*C[VE1+12]));
  float e1 = __expf(lrelu(ssv.y + sdv.y + a.x*C[VE1+1] + a.y*C[VE1+5] + a.z*C[VE1+9]  + a.w*C[VE1+13]));
  float e2 = __expf(lrelu(ssv.z + sdv.z + a.x*C[VE1+2] + a.y*C[VE1+6] + a.z*C[VE1+10] + a.w*C[VE1+14]));
  float e3 = __expf(lrelu(ssv.w + sdv.w + a.x*C[VE1+3] + a.y*C[VE1+7] + a.z*C[VE1+11] + a.w*C[VE1+15]));
  exf[p] = make_float4(e0, e1, e2, e3);
}

// ---- per-node: self-loop attr = mean of real-edge attrs + self alpha --------
__global__ void k_loopself(const int* __restrict__ csr, int4* __restrict__ epk,
                           const float* __restrict__ ss1, const float* __restrict__ sd1,
                           const float* __restrict__ C, float4* __restrict__ exf){
  int n = blockIdx.x * 256 + threadIdx.x;
  if (n >= NN) return;
  int a = csr[n], b = csr[n + 1];
  int deg = b - a - 1;
  float s0 = 0.f, s1 = 0.f, s2 = 0.f, s3 = 0.f;
  for (int p = a; p < b - 1; ++p){
    int4 v = epk[p];
    s0 += b2f((unsigned)v.z & 0xffffu); s1 += b2f((unsigned)v.z >> 16);
    s2 += b2f((unsigned)v.w & 0xffffu); s3 += b2f((unsigned)v.w >> 16);
  }
  float inv = 1.f / (float)(deg > 1 ? deg : 1);
  float m0 = s0*inv, m1 = s1*inv, m2 = s2*inv, m3 = s3*inv;
  epk[b - 1] = make_int4(n, n, (int)pk2(m0, m1), (int)pk2(m2, m3));
  float4 ssv = *(const float4*)&ss1[(size_t)n * 4];
  float4 sdv = *(const float4*)&sd1[(size_t)n * 4];
  float e0 = __expf(lrelu(ssv.x + sdv.x + m0*C[VE1+0] + m1*C[VE1+4] + m2*C[VE1+8]  + m3*C[VE1+12]));
  float e1 = __expf(lrelu(ssv.y + sdv.y + m0*C[VE1+1] + m1*C[VE1+5] + m2*C[VE1+9]  + m3*C[VE1+13]));
  float e2 = __expf(lrelu(ssv.z + sdv.z + m0*C[VE1+2] + m1*C[VE1+6] + m2*C[VE1+10] + m3*C[VE1+14]));
  float e3 = __expf(lrelu(ssv.w + sdv.w + m0*C[VE1+3] + m1*C[VE1+7] + m2*C[VE1+11] + m3*C[VE1+15]));
  exf[b - 1] = make_float4(e0, e1, e2, e3);
}

// ---- tiny weight pre-reductions --------------------------------------------
__global__ void k_prep(const float* __restrict__ W1, const float* __restrict__ as1,
                       const float* __restrict__ ad1, const float* __restrict__ We1,
                       const float* __restrict__ ae1, const float* __restrict__ W2,
                       const float* __restrict__ as2, const float* __restrict__ ad2,
                       const float* __restrict__ We2, const float* __restrict__ ae2,
                       float* __restrict__ C){
  int t = threadIdx.x;                       // block of 512
  if (t < 280){
    int k = t >> 2, h = t & 3;
    float s = 0.f, d = 0.f;
    for (int dd = 0; dd < 128; ++dd){
      float w = W1[k*512 + h*128 + dd];
      s += w * as1[h*128 + dd];
      d += w * ad1[h*128 + dd];
    }
    C[VS1 + t] = s; C[VD1 + t] = d;
  }
  if (t < 16){
    int k = t >> 2, h = t & 3;
    float s = 0.f;
    for (int dd = 0; dd < 128; ++dd) s += We1[k*512 + h*128 + dd] * ae1[h*128 + dd];
    C[VE1 + t] = s;
  }
  if (t < 4){
    float s = 0.f;
    for (int dd = 0; dd < 128; ++dd) s += We2[t*128 + dd] * ae2[dd];
    C[VE2 + t] = s;
  }
  {
    float s = 0.f, d = 0.f;
    for (int dd = 0; dd < 128; ++dd){
      float w = W2[t*128 + dd];
      s += w * as2[dd];
      d += w * ad2[dd];
    }
    C[VS2 + t] = s; C[VD2 + t] = d;
  }
}

// ---- transpose + bf16-cast weights -----------------------------------------
__global__ void k_tw(const float* __restrict__ W1, const float* __restrict__ W2,
                     unsigned short* __restrict__ W1t, unsigned short* __restrict__ W2t){
  int i = blockIdx.x * 256 + threadIdx.x;
  if (i < 4*128*KP1){
    int k = i % KP1, n = (i / KP1) & 127, h = i / (KP1*128);
    float v = (k < FIN) ? W1[k*512 + h*128 + n] : 0.f;
    W1t[i] = f2b(v);
  } else {
    int j = i - 4*128*KP1;
    if (j < 128*512){
      int k = j & 511, n = j >> 9;
      W2t[j] = f2b(W2[k*128 + n]);
    }
  }
}

// ---- fused: nf -> bf16 (pitch 72) + layer1 attention scalars ----------------
__global__ __launch_bounds__(256) void k_cnfs1(const float* __restrict__ nf,
    const float* __restrict__ C, unsigned short* __restrict__ nfb,
    float* __restrict__ ss1, float* __restrict__ sd1){
  int lane = threadIdx.x & 63, w = threadIdx.x >> 6;
  int n = blockIdx.x * 4 + w;
  if (n >= NN) return;
  int c0 = lane * 2;
  bool act = lane < 35;                 // cols 0..69
  float v0 = 0.f, v1 = 0.f;
  if (act){
    v0 = nf[(size_t)n * FIN + c0];
    v1 = nf[(size_t)n * FIN + c0 + 1];
  }
  if (lane < 36) *(unsigned*)&nfb[(size_t)n * NFP + c0] = act ? pk2(v0, v1) : 0u;
  float sh[4] = {0,0,0,0}, dh[4] = {0,0,0,0};
  if (act){
    float4 cs0 = *(const float4*)&C[VS1 + c0*4];
    float4 cs1 = *(const float4*)&C[VS1 + (c0+1)*4];
    float4 cd0 = *(const float4*)&C[VD1 + c0*4];
    float4 cd1 = *(const float4*)&C[VD1 + (c0+1)*4];
    sh[0] = v0*cs0.x + v1*cs1.x; sh[1] = v0*cs0.y + v1*cs1.y;
    sh[2] = v0*cs0.z + v1*cs1.z; sh[3] = v0*cs0.w + v1*cs1.w;
    dh[0] = v0*cd0.x + v1*cd1.x; dh[1] = v0*cd0.y + v1*cd1.y;
    dh[2] = v0*cd0.z + v1*cd1.z; dh[3] = v0*cd0.w + v1*cd1.w;
  }
  #pragma unroll
  for (int o = 32; o; o >>= 1){
    #pragma unroll
    for (int h = 0; h < 4; ++h){
      sh[h] += __shfl_xor(sh[h], o);
      dh[h] += __shfl_xor(dh[h], o);
    }
  }
  if (lane == 0){
    *(float4*)&ss1[(size_t)n*4] = make_float4(sh[0], sh[1], sh[2], sh[3]);
    *(float4*)&sd1[(size_t)n*4] = make_float4(dh[0], dh[1], dh[2], dh[3]);
  }
}

// ---- edge-parallel alpha (layer 2) ------------------------------------------
__global__ void k_al2(const int4* __restrict__ epk, const float* __restrict__ ss2,
                      const float* __restrict__ sd2, const float* __restrict__ C,
                      float* __restrict__ ex2){
  int p = blockIdx.x * 256 + threadIdx.x;
  if (p >= ET) return;
  int4 pk = epk[p];
  int s = pk.x, d = pk.y;
  float ax = b2f((unsigned)pk.z & 0xffffu), ay = b2f((unsigned)pk.z >> 16);
  float az = b2f((unsigned)pk.w & 0xffffu), aw = b2f((unsigned)pk.w >> 16);
  ex2[p] = __expf(lrelu(ss2[s] + sd2[d] +
             ax*C[VE2] + ay*C[VE2+1] + az*C[VE2+2] + aw*C[VE2+3]));
}

// ---- FUSED two-stage GEMM, flatmm-style: B direct from global (L2-hot), ----
// ---- A direct from global, xt transpose in LDS, ONE barrier per block. -----
// stage1: xt[32][512] = gelu(agg @ W1 + b1) + ss2/sd2 from register values
// stage2: xs2[32][128] = xt @ W2t^T (K=512)
__global__ __launch_bounds__(256) void k_gemm12(
    const unsigned short* __restrict__ agg, const unsigned short* __restrict__ W1t,
    const unsigned short* __restrict__ W2t, const float* __restrict__ b1,
    const float* __restrict__ Cv, unsigned short* __restrict__ xs2b,
    float* __restrict__ ss2, float* __restrict__ sd2){
  __shared__ unsigned short xt[32 * 520];   // 33.3 KB
  __shared__ float ssp[32][2], sdp[32][2];
  int tid = threadIdx.x, lane = tid & 63, w = tid >> 6;
  int wm = w & 1, wn = w >> 1;
  int m15 = lane & 15, rq = lane >> 4;
  int r0 = blockIdx.x * 32;
  int lrow = wm * 16 + m15;
  int grow = r0 + lrow;
  int growc = grow < NN ? grow : NN - 1;
  constexpr size_t HS = (size_t)NN * KP1;
  float s2a = 0.f, s2d = 0.f;
  // ---------------- stage 1 (no barriers) ----------------
  #pragma unroll
  for (int h = 0; h < 4; ++h){
    const unsigned short* Ah = agg + (size_t)h * HS + (size_t)growc * KP1;
    const unsigned short* Wh = W1t + h * 128 * KP1;
    f4v acc[4] = {};
    #pragma unroll
    for (int kk = 0; kk < 3; ++kk){
      int k0 = kk * 32;
      s8v af = *(const s8v*)&Ah[k0 + rq*8];
      #pragma unroll
      for (int ni = 0; ni < 4; ++ni){
        s8v bf = *(const s8v*)&Wh[(wn*64 + ni*16 + m15)*KP1 + k0 + rq*8];
        acc[ni] = __builtin_amdgcn_mfma_f32_16x16x32_bf16(bf, af, acc[ni], 0, 0, 0);
      }
    }
    #pragma unroll
    for (int ni = 0; ni < 4; ++ni){
      int cb = h*128 + wn*64 + ni*16 + rq*4;
      float4 bv = *(const float4*)&b1[cb];
      float v0 = gelu_fast(acc[ni][0] + bv.x);
      float v1 = gelu_fast(acc[ni][1] + bv.y);
      float v2 = gelu_fast(acc[ni][2] + bv.z);
      float v3 = gelu_fast(acc[ni][3] + bv.w);
      float4 cs = *(const float4*)&Cv[VS2 + cb];
      float4 cd = *(const float4*)&Cv[VD2 + cb];
      s2a += v0*cs.x + v1*cs.y + v2*cs.z + v3*cs.w;
      s2d += v0*cd.x + v1*cd.y + v2*cd.z + v3*cd.w;
      *(uint2*)&xt[lrow*520 + cb] = make_uint2(pk2(v0,v1), pk2(v2,v3));
    }
  }
  // ss2/sd2: reduce over rq lanes (cols split across rq), then across wn waves
  s2a += __shfl_xor(s2a, 16); s2a += __shfl_xor(s2a, 32);
  s2d += __shfl_xor(s2d, 16); s2d += __shfl_xor(s2d, 32);
  if (rq == 0){ ssp[lrow][wn] = s2a; sdp[lrow][wn] = s2d; }
  __syncthreads();                          // the ONE barrier: xt + ssp visible
  if (tid < 32 && r0 + tid < NN){
    ss2[r0 + tid] = ssp[tid][0] + ssp[tid][1];
    sd2[r0 + tid] = sdp[tid][0] + sdp[tid][1];
  }
  // ---------------- stage 2 (no barriers) ----------------
  f4v acc2[4] = {};
  #pragma unroll 4
  for (int k0 = 0; k0 < 512; k0 += 32){
    s8v af = *(const s8v*)&xt[lrow*520 + k0 + rq*8];
    #pragma unroll
    for (int ni = 0; ni < 4; ++ni){
      s8v bf = *(const s8v*)&W2t[(wn*64 + ni*16 + m15)*512 + k0 + rq*8];
      acc2[ni] = __builtin_amdgcn_mfma_f32_16x16x32_bf16(bf, af, acc2[ni], 0, 0, 0);
    }
  }
  if (grow < NN){
    #pragma unroll
    for (int ni = 0; ni < 4; ++ni){
      int gc = wn*64 + ni*16 + rq*4;
      *(uint2*)&xs2b[(size_t)grow*128 + gc] =
          make_uint2(pk2(acc2[ni][0], acc2[ni][1]), pk2(acc2[ni][2], acc2[ni][3]));
    }
  }
}

// ---- layer1 aggregation: wave/node, 2-edge pipelined gather -----------------
__global__ __launch_bounds__(256) void k_aggnf(const int* __restrict__ csr,
    const int4* __restrict__ epk, const float4* __restrict__ exf,
    const unsigned short* __restrict__ nfb, unsigned short* __restrict__ agg){
  int lane = threadIdx.x & 63, w = threadIdx.x >> 6;
  int n = blockIdx.x * 4 + w;
  if (n >= NN) return;
  int off = __builtin_amdgcn_readfirstlane(csr[n]);
  int end = __builtin_amdgcn_readfirstlane(csr[n + 1]);
  int col = lane * 2;
  bool act = lane < 36;
  float d0=0,d1=0,d2=0,d3=0;
  float a00=0,a01=0,a10=0,a11=0,a20=0,a21=0,a30=0,a31=0;
  int p = off;
  for (; p + 2 <= end; p += 2){
    int s0 = epk[p].x, s1 = epk[p+1].x;
    float4 e0 = exf[p], e1 = exf[p+1];
    unsigned u0 = 0, u1 = 0;
    if (act){
      u0 = *(const unsigned*)&nfb[(size_t)s0 * NFP + col];
      u1 = *(const unsigned*)&nfb[(size_t)s1 * NFP + col];
    }
    d0 += e0.x + e1.x; d1 += e0.y + e1.y; d2 += e0.z + e1.z; d3 += e0.w + e1.w;
    float v00 = b2f(u0 & 0xffffu), v01 = b2f(u0 >> 16);
    float v10 = b2f(u1 & 0xffffu), v11 = b2f(u1 >> 16);
    a00 += e0.x*v00 + e1.x*v10; a01 += e0.x*v01 + e1.x*v11;
    a10 += e0.y*v00 + e1.y*v10; a11 += e0.y*v01 + e1.y*v11;
    a20 += e0.z*v00 + e1.z*v10; a21 += e0.z*v01 + e1.z*v11;
    a30 += e0.w*v00 + e1.w*v10; a31 += e0.w*v01 + e1.w*v11;
  }
  if (p < end){
    int s0 = epk[p].x;
    float4 e0 = exf[p];
    unsigned u0 = 0;
    if (act) u0 = *(const unsigned*)&nfb[(size_t)s0 * NFP + col];
    d0 += e0.x; d1 += e0.y; d2 += e0.z; d3 += e0.w;
    float v00 = b2f(u0 & 0xffffu), v01 = b2f(u0 >> 16);
    a00 += e0.x*v00; a01 += e0.x*v01;
    a10 += e0.y*v00; a11 += e0.y*v01;
    a20 += e0.z*v00; a21 += e0.z*v01;
    a30 += e0.w*v00; a31 += e0.w*v01;
  }
  float i0 = 1.f/(d0+1e-16f), i1 = 1.f/(d1+1e-16f);
  float i2 = 1.f/(d2+1e-16f), i3 = 1.f/(d3+1e-16f);
  constexpr size_t HS = (size_t)NN * KP1;
  size_t base = (size_t)n * KP1 + col;
  if (act){
    *(unsigned*)&agg[base]        = pk2(a00*i0, a01*i0);
    *(unsigned*)&agg[base +   HS] = pk2(a10*i1, a11*i1);
    *(unsigned*)&agg[base + 2*HS] = pk2(a20*i2, a21*i2);
    *(unsigned*)&agg[base + 3*HS] = pk2(a30*i3, a31*i3);
  } else if (lane < 48){                // zero cols 72..95
    *(unsigned*)&agg[base]        = 0u;
    *(unsigned*)&agg[base +   HS] = 0u;
    *(unsigned*)&agg[base + 2*HS] = 0u;
    *(unsigned*)&agg[base + 3*HS] = 0u;
  }
}

// ---- layer2 aggregation: 4-edge pipelined gather + GELU + LN + projections --
__global__ __launch_bounds__(256) void k_agg2(
    const int* __restrict__ csr, const int4* __restrict__ epk,
    const float* __restrict__ ex2, const unsigned short* __restrict__ xs2b,
    const float* __restrict__ b2, const float* __restrict__ lng,
    const float* __restrict__ lnb, const float* __restrict__ pw,
    const float* __restrict__ pb, const float* __restrict__ dwm,
    const float* __restrict__ dbv, float* __restrict__ out){
  int lane = threadIdx.x & 63, w = threadIdx.x >> 6;
  int n = blockIdx.x * 4 + w;
  if (n >= NN) return;
  int off = __builtin_amdgcn_readfirstlane(csr[n]);
  int end = __builtin_amdgcn_readfirstlane(csr[n + 1]);
  int c0 = lane * 2;
  float acc0 = 0.f, acc1 = 0.f, den = 0.f;
  int p = off;
  for (; p + 4 <= end; p += 4){
    int s0 = epk[p].x, s1 = epk[p+1].x, s2 = epk[p+2].x, s3 = epk[p+3].x;
    float e0 = ex2[p], e1 = ex2[p+1], e2 = ex2[p+2], e3 = ex2[p+3];
    unsigned u0 = *(const unsigned*)&xs2b[(size_t)s0 * 128 + c0];
    unsigned u1 = *(const unsigned*)&xs2b[(size_t)s1 * 128 + c0];
    unsigned u2 = *(const unsigned*)&xs2b[(size_t)s2 * 128 + c0];
    unsigned u3 = *(const unsigned*)&xs2b[(size_t)s3 * 128 + c0];
    den += (e0 + e1) + (e2 + e3);
    acc0 += e0*b2f(u0 & 0xffffu) + e1*b2f(u1 & 0xffffu)
          + e2*b2f(u2 & 0xffffu) + e3*b2f(u3 & 0xffffu);
    acc1 += e0*b2f(u0 >> 16) + e1*b2f(u1 >> 16)
          + e2*b2f(u2 >> 16) + e3*b2f(u3 >> 16);
  }
  for (; p + 2 <= end; p += 2){
    int s0 = epk[p].x, s1 = epk[p+1].x;
    float e0 = ex2[p], e1 = ex2[p+1];
    unsigned u0 = *(const unsigned*)&xs2b[(size_t)s0 * 128 + c0];
    unsigned u1 = *(const unsigned*)&xs2b[(size_t)s1 * 128 + c0];
    den += e0 + e1;
    acc0 += e0*b2f(u0 & 0xffffu) + e1*b2f(u1 & 0xffffu);
    acc1 += e0*b2f(u0 >> 16) + e1*b2f(u1 >> 16);
  }
  if (p < end){
    int s0 = epk[p].x;
    float e0 = ex2[p];
    unsigned u0 = *(const unsigned*)&xs2b[(size_t)s0 * 128 + c0];
    den += e0;
    acc0 += e0*b2f(u0 & 0xffffu);
    acc1 += e0*b2f(u0 >> 16);
  }
  float invd = 1.f / (den + 1e-16f);
  float g0 = gelu_fast(acc0 * invd + b2[c0]);
  float g1 = gelu_fast(acc1 * invd + b2[c0 + 1]);
  float s = g0 + g1;
  #pragma unroll
  for (int o = 32; o; o >>= 1) s += __shfl_xor(s, o);
  float mu = s * (1.f / 128.f);
  float e0 = g0 - mu, e1 = g1 - mu;
  float q = e0*e0 + e1*e1;
  #pragma unroll
  for (int o = 32; o; o >>= 1) q += __shfl_xor(q, o);
  float rstd = rsqrtf(q * (1.f / 128.f) + 1e-5f);
  float y0 = e0 * rstd * lng[c0] + lnb[c0];
  float y1 = e1 * rstd * lng[c0 + 1] + lnb[c0 + 1];
  float pr[12];
  #pragma unroll
  for (int jj = 0; jj < 8; ++jj) pr[jj] = y0 * pw[c0*8 + jj] + y1 * pw[(c0+1)*8 + jj];
  #pragma unroll
  for (int jj = 0; jj < 4; ++jj) pr[8+jj] = y0 * dwm[c0*4 + jj] + y1 * dwm[(c0+1)*4 + jj];
  #pragma unroll
  for (int o = 32; o; o >>= 1)
    #pragma unroll
    for (int jj = 0; jj < 12; ++jj) pr[jj] += __shfl_xor(pr[jj], o);
  if (lane == 0){
    #pragma unroll
    for (int jj = 0; jj < 8; ++jj) out[(size_t)n*8 + jj] = pr[jj] + pb[jj];
    #pragma unroll
    for (int jj = 0; jj < 4; ++jj) out[(size_t)NN*8 + (size_t)n*4 + jj] = pr[8+jj] + dbv[jj];
  }
}

extern "C" void kernel_launch(void* const* d_in, const int* in_sizes, int n_in,
                              void* d_out, int out_size, void* d_ws, size_t ws_size,
                              hipStream_t stream){
  const float* nf  = (const float*)d_in[0];
  const int*   ei  = (const int*)  d_in[1];
  const float* ea  = (const float*)d_in[2];
  const float* W1  = (const float*)d_in[3];
  const float* as1 = (const float*)d_in[4];
  const float* ad1 = (const float*)d_in[5];
  const float* We1 = (const float*)d_in[6];
  const float* ae1 = (const float*)d_in[7];
  const float* b1  = (const float*)d_in[8];
  const float* W2  = (const float*)d_in[9];
  const float* as2 = (const float*)d_in[10];
  const float* ad2 = (const float*)d_in[11];
  const float* We2 = (const float*)d_in[12];
  const float* ae2 = (const float*)d_in[13];
  const float* b2  = (const float*)d_in[14];
  const float* lng = (const float*)d_in[15];
  const float* lnb = (const float*)d_in[16];
  const float* pw  = (const float*)d_in[17];
  const float* pb  = (const float*)d_in[18];
  const float* dw  = (const float*)d_in[19];
  const float* db  = (const float*)d_in[20];
  float* out = (float*)d_out;

  float* wf = (float*)d_ws;
  int*      cnt  = (int*)     (wf + CNT_O);
  int*      csr  = (int*)     (wf + CSR_O);
  int*      bsum = (int*)     (wf + BSUM_O);
  int*      boff = (int*)     (wf + BOFF_O);
  int4*     epk  = (int4*)    (wf + EPK_O);
  float4*   exf1 = (float4*)  (wf + EXF1_O);
  float*    ex2  =            (wf + EXF2_O);
  float*    ss1  =            (wf + SS1_O);
  float*    sd1  =            (wf + SD1_O);
  float*    ss2  =            (wf + SS2_O);
  float*    sd2  =            (wf + SD2_O);
  float*    Cc   =            (wf + CST_O);
  unsigned short* W1t = (unsigned short*)(wf + W1T_O);
  unsigned short* W2t = (unsigned short*)(wf + W2T_O);
  unsigned short* nfb = (unsigned short*)(wf + NFB_O);
  unsigned short* agg = (unsigned short*)(wf + AGG_O);
  unsigned short* xs2b= (unsigned short*)(wf + XS2_O);

  hipMemsetAsync(cnt, 0, NN * sizeof(int), stream);
  k_prep<<<1, 512, 0, stream>>>(W1, as1, ad1, We1, ae1, W2, as2, ad2, We2, ae2, Cc);
  k_tw<<<(4*128*KP1 + 128*512 + 255) / 256, 256, 0, stream>>>(W1, W2, W1t, W2t);
  k_cnfs1<<<(NN + 3) / 4, 256, 0, stream>>>(nf, Cc, nfb, ss1, sd1);
  k_deg<<<(NE + 255) / 256, 256, 0, stream>>>(ei, cnt);
  k_scan1<<<SCB, 256, 0, stream>>>(cnt, bsum);
  k_scan2<<<1, 256, 0, stream>>>(bsum, boff);
  k_scan3<<<SCB, 256, 0, stream>>>(cnt, boff, csr);
  k_fill<<<(NE + 255) / 256, 256, 0, stream>>>(ei, ea, csr, cnt, epk, ss1, sd1, Cc, exf1);
  k_loopself<<<(NN + 255) / 256, 256, 0, stream>>>(csr, epk, ss1, sd1, Cc, exf1);
  k_aggnf<<<(NN + 3) / 4, 256, 0, stream>>>(csr, epk, exf1, nfb, agg);
  k_gemm12<<<(NN + 31) / 32, 256, 0, stream>>>(agg, W1t, W2t, b1, Cc, xs2b, ss2, sd2);
  k_al2<<<(ET + 255) / 256, 256, 0, stream>>>(epk, ss2, sd2, Cc, ex2);
  k_agg2<<<(NN + 3) / 4, 256, 0, stream>>>(csr, epk, ex2, xs2b,
                                           b2, lng, lnb, pw, pb, dw, db, out);
}

// Round 12
// 363.060 us; speedup vs baseline: 1.0748x; 1.0748x over previous
//
#include <hip/hip_runtime.h>
#include <hip/hip_bf16.h>
#include <math.h>

#define NN 50000
#define NE 400000
#define FIN 70
#define EDIM 4
#define HIDD 128
#define NHEAD 4
constexpr int ET = NE + NN;
constexpr int KP1 = 96;           // layer-1 K padded (70 -> 96)
constexpr int NFP = 72;           // nf bf16 row pitch
constexpr int SCB = (NN + 255) / 256;   // scan blocks = 196

constexpr size_t al4(size_t x){ return (x + 3) & ~size_t(3); }
// ws offsets in 4-byte words
constexpr size_t CNT_O   = 0;                          // int[NN] (zeroed each call)
constexpr size_t ZEND    = al4(CNT_O + NN);
constexpr size_t CSR_O   = ZEND;                       // int[NN+1]
constexpr size_t BSUM_O  = al4(CSR_O + NN + 1);        // int[256]
constexpr size_t BOFF_O  = al4(BSUM_O + 256);          // int[256]
constexpr size_t EPK_O   = al4(BOFF_O + 256);          // int4[ET] {s,d,ea01,ea23}
constexpr size_t EXF1_O  = al4(EPK_O + (size_t)ET*4);  // float4[ET] exp scores L1
constexpr size_t EXF2_O  = al4(EXF1_O + (size_t)ET*4); // f32[ET]    exp scores L2
constexpr size_t SS1_O   = al4(EXF2_O + ET);           // f32[NN*4]
constexpr size_t SD1_O   = al4(SS1_O + (size_t)NN*4);
constexpr size_t SS2_O   = al4(SD1_O + (size_t)NN*4);  // f32[NN]
constexpr size_t SD2_O   = al4(SS2_O + NN);
constexpr size_t CST_O   = al4(SD2_O + NN);            // f32[2048]
constexpr size_t W1T_O   = al4(CST_O + 2048);          // bf16[4][128][96]
constexpr size_t W2T_O   = al4(W1T_O + 4*128*KP1/2);   // bf16[128][512]
constexpr size_t NFB_O   = al4(W2T_O + 128*512/2);     // bf16[NN][72]
constexpr size_t AGG_O   = al4(NFB_O + (size_t)NN*NFP/2);   // bf16[4][NN][96]
constexpr size_t XS2_O   = al4(AGG_O + (size_t)4*NN*KP1/2); // bf16[NN][128]

// const-block sub-offsets (words, within CST)
constexpr int VS1 = 0;    // [70][4]
constexpr int VD1 = 320;  // [70][4]
constexpr int VE1 = 640;  // [4][4]
constexpr int VE2 = 656;  // [4]
constexpr int VS2 = 704;  // [512]
constexpr int VD2 = 1216; // [512]

typedef short s8v __attribute__((ext_vector_type(8)));
typedef float f4v __attribute__((ext_vector_type(4)));

__device__ __forceinline__ unsigned short f2b(float v){
  __hip_bfloat16 b = __float2bfloat16(v);
  return *(unsigned short*)&b;
}
__device__ __forceinline__ float b2f(unsigned u_lo16){
  return __uint_as_float(u_lo16 << 16);
}
__device__ __forceinline__ unsigned pk2(float lo, float hi){
  return (unsigned)f2b(lo) | ((unsigned)f2b(hi) << 16);
}
__device__ __forceinline__ float lrelu(float x){ return x > 0.f ? x : 0.2f * x; }

// erf via A&S 7.1.26 (|err|<1.5e-7), one fast v_exp — avoids libm erff
__device__ __forceinline__ float gelu_fast(float x){
  float z = x * 0.70710678118654752440f;
  float a = fabsf(z);
  float t = 1.f / (1.f + 0.3275911f * a);
  float p = ((((1.061405429f*t - 1.453152027f)*t + 1.421413741f)*t
              - 0.284496736f)*t + 0.254829592f)*t;
  float erfv = 1.f - p * __expf(-a * a);
  erfv = copysignf(erfv, z);
  return 0.5f * x * (1.f + erfv);
}

// ---- degree histogram: ONE atomic per edge ----------------------------------
__global__ void k_deg(const int* __restrict__ ei, int* __restrict__ cnt){
  int e = blockIdx.x * 256 + threadIdx.x;
  if (e >= NE) return;
  atomicAdd(&cnt[ei[NE + e]], 1);
}

// ---- CSR build: 3-phase scan of (cnt+1) -------------------------------------
__global__ void k_scan1(const int* __restrict__ cnt, int* __restrict__ bsum){
  __shared__ int ws[4];
  int t = threadIdx.x, lane = t & 63, w = t >> 6;
  int i = blockIdx.x * 256 + t;
  int v = (i < NN) ? cnt[i] + 1 : 0;
  for (int o = 32; o; o >>= 1) v += __shfl_down(v, o);
  if (lane == 0) ws[w] = v;
  __syncthreads();
  if (t == 0) bsum[blockIdx.x] = ws[0] + ws[1] + ws[2] + ws[3];
}

__global__ void k_scan2(const int* __restrict__ bsum, int* __restrict__ boff){
  __shared__ int ws[4];
  int t = threadIdx.x, lane = t & 63, w = t >> 6;
  int v = (t < SCB) ? bsum[t] : 0;
  int x = v;
  #pragma unroll
  for (int o = 1; o < 64; o <<= 1){ int u = __shfl_up(x, o); if (lane >= o) x += u; }
  if (lane == 63) ws[w] = x;
  __syncthreads();
  if (w == 0 && lane < 4){
    int y = ws[lane];
    #pragma unroll
    for (int o = 1; o < 4; o <<= 1){ int u = __shfl_up(y, o); if (lane >= o) y += u; }
    ws[lane] = y;
  }
  __syncthreads();
  int incl = x + (w > 0 ? ws[w - 1] : 0);
  if (t < SCB) boff[t] = incl - v;
}

__global__ void k_scan3(const int* __restrict__ cnt, const int* __restrict__ boff,
                        int* __restrict__ csr){
  __shared__ int ws[4];
  int t = threadIdx.x, lane = t & 63, w = t >> 6;
  int i = blockIdx.x * 256 + t;
  int v = (i < NN) ? cnt[i] + 1 : 0;
  int x = v;
  #pragma unroll
  for (int o = 1; o < 64; o <<= 1){ int u = __shfl_up(x, o); if (lane >= o) x += u; }
  if (lane == 63) ws[w] = x;
  __syncthreads();
  if (w == 0 && lane < 4){
    int y = ws[lane];
    #pragma unroll
    for (int o = 1; o < 4; o <<= 1){ int u = __shfl_up(y, o); if (lane >= o) y += u; }
    ws[lane] = y;
  }
  __syncthreads();
  if (i < NN) csr[i + 1] = boff[blockIdx.x] + (w > 0 ? ws[w - 1] : 0) + x;
  if (i == 0) csr[0] = 0;
}

// ---- fill CSR slots + FUSED layer-1 alpha; consumes cnt -> 0 ----------------
__global__ void k_fill(const int* __restrict__ ei, const float* __restrict__ ea,
                       const int* __restrict__ csr, int* __restrict__ cnt,
                       int4* __restrict__ epk, const float* __restrict__ ss1,
                       const float* __restrict__ sd1, const float* __restrict__ C,
                       float4* __restrict__ exf){
  int e = blockIdx.x * 256 + threadIdx.x;
  if (e >= NE) return;
  int s = ei[e], d = ei[NE + e];
  int r = atomicSub(&cnt[d], 1);        // r in [deg..1]
  int p = csr[d] + r - 1;
  float4 a = *(const float4*)&ea[(size_t)e * 4];
  epk[p] = make_int4(s, d, (int)pk2(a.x, a.y), (int)pk2(a.z, a.w));
  float4 ssv = *(const float4*)&ss1[(size_t)s * 4];
  float4 sdv = *(const float4*)&sd1[(size_t)d * 4];
  float e0 = __expf(lrelu(ssv.x + sdv.x + a.x*C[VE1+0] + a.y*C[VE1+4] + a.z*C[VE1+8]  + a.w*C[VE1+12]));
  float e1 = __expf(lrelu(ssv.y + sdv.y + a.x*C[VE1+1] + a.y*C[VE1+5] + a.z*C[VE1+9]  + a.w*C[VE1+13]));
  float e2 = __expf(lrelu(ssv.z + sdv.z + a.x*C[VE1+2] + a.y*C[VE1+6] + a.z*C[VE1+10] + a.w*C[VE1+14]));
  float e3 = __expf(lrelu(ssv.w + sdv.w + a.x*C[VE1+3] + a.y*C[VE1+7] + a.z*C[VE1+11] + a.w*C[VE1+15]));
  exf[p] = make_float4(e0, e1, e2, e3);
}

// ---- per-node: self-loop attr = mean of real-edge attrs + self alpha --------
__global__ void k_loopself(const int* __restrict__ csr, int4* __restrict__ epk,
                           const float* __restrict__ ss1, const float* __restrict__ sd1,
                           const float* __restrict__ C, float4* __restrict__ exf){
  int n = blockIdx.x * 256 + threadIdx.x;
  if (n >= NN) return;
  int a = csr[n], b = csr[n + 1];
  int deg = b - a - 1;
  float s0 = 0.f, s1 = 0.f, s2 = 0.f, s3 = 0.f;
  for (int p = a; p < b - 1; ++p){
    int4 v = epk[p];
    s0 += b2f((unsigned)v.z & 0xffffu); s1 += b2f((unsigned)v.z >> 16);
    s2 += b2f((unsigned)v.w & 0xffffu); s3 += b2f((unsigned)v.w >> 16);
  }
  float inv = 1.f / (float)(deg > 1 ? deg : 1);
  float m0 = s0*inv, m1 = s1*inv, m2 = s2*inv, m3 = s3*inv;
  epk[b - 1] = make_int4(n, n, (int)pk2(m0, m1), (int)pk2(m2, m3));
  float4 ssv = *(const float4*)&ss1[(size_t)n * 4];
  float4 sdv = *(const float4*)&sd1[(size_t)n * 4];
  float e0 = __expf(lrelu(ssv.x + sdv.x + m0*C[VE1+0] + m1*C[VE1+4] + m2*C[VE1+8]  + m3*C[VE1+12]));
  float e1 = __expf(lrelu(ssv.y + sdv.y + m0*C[VE1+1] + m1*C[VE1+5] + m2*C[VE1+9]  + m3*C[VE1+13]));
  float e2 = __expf(lrelu(ssv.z + sdv.z + m0*C[VE1+2] + m1*C[VE1+6] + m2*C[VE1+10] + m3*C[VE1+14]));
  float e3 = __expf(lrelu(ssv.w + sdv.w + m0*C[VE1+3] + m1*C[VE1+7] + m2*C[VE1+11] + m3*C[VE1+15]));
  exf[b - 1] = make_float4(e0, e1, e2, e3);
}

// ---- tiny weight pre-reductions --------------------------------------------
__global__ void k_prep(const float* __restrict__ W1, const float* __restrict__ as1,
                       const float* __restrict__ ad1, const float* __restrict__ We1,
                       const float* __restrict__ ae1, const float* __restrict__ W2,
                       const float* __restrict__ as2, const float* __restrict__ ad2,
                       const float* __restrict__ We2, const float* __restrict__ ae2,
                       float* __restrict__ C){
  int t = threadIdx.x;                       // block of 512
  if (t < 280){
    int k = t >> 2, h = t & 3;
    float s = 0.f, d = 0.f;
    for (int dd = 0; dd < 128; ++dd){
      float w = W1[k*512 + h*128 + dd];
      s += w * as1[h*128 + dd];
      d += w * ad1[h*128 + dd];
    }
    C[VS1 + t] = s; C[VD1 + t] = d;
  }
  if (t < 16){
    int k = t >> 2, h = t & 3;
    float s = 0.f;
    for (int dd = 0; dd < 128; ++dd) s += We1[k*512 + h*128 + dd] * ae1[h*128 + dd];
    C[VE1 + t] = s;
  }
  if (t < 4){
    float s = 0.f;
    for (int dd = 0; dd < 128; ++dd) s += We2[t*128 + dd] * ae2[dd];
    C[VE2 + t] = s;
  }
  {
    float s = 0.f, d = 0.f;
    for (int dd = 0; dd < 128; ++dd){
      float w = W2[t*128 + dd];
      s += w * as2[dd];
      d += w * ad2[dd];
    }
    C[VS2 + t] = s; C[VD2 + t] = d;
  }
}

// ---- transpose + bf16-cast weights -----------------------------------------
__global__ void k_tw(const float* __restrict__ W1, const float* __restrict__ W2,
                     unsigned short* __restrict__ W1t, unsigned short* __restrict__ W2t){
  int i = blockIdx.x * 256 + threadIdx.x;
  if (i < 4*128*KP1){
    int k = i % KP1, n = (i / KP1) & 127, h = i / (KP1*128);
    float v = (k < FIN) ? W1[k*512 + h*128 + n] : 0.f;
    W1t[i] = f2b(v);
  } else {
    int j = i - 4*128*KP1;
    if (j < 128*512){
      int k = j & 511, n = j >> 9;
      W2t[j] = f2b(W2[k*128 + n]);
    }
  }
}

// ---- fused: nf -> bf16 (pitch 72) + layer1 attention scalars ----------------
__global__ __launch_bounds__(256) void k_cnfs1(const float* __restrict__ nf,
    const float* __restrict__ C, unsigned short* __restrict__ nfb,
    float* __restrict__ ss1, float* __restrict__ sd1){
  int lane = threadIdx.x & 63, w = threadIdx.x >> 6;
  int n = blockIdx.x * 4 + w;
  if (n >= NN) return;
  int c0 = lane * 2;
  bool act = lane < 35;                 // cols 0..69
  float v0 = 0.f, v1 = 0.f;
  if (act){
    v0 = nf[(size_t)n * FIN + c0];
    v1 = nf[(size_t)n * FIN + c0 + 1];
  }
  if (lane < 36) *(unsigned*)&nfb[(size_t)n * NFP + c0] = act ? pk2(v0, v1) : 0u;
  float sh[4] = {0,0,0,0}, dh[4] = {0,0,0,0};
  if (act){
    float4 cs0 = *(const float4*)&C[VS1 + c0*4];
    float4 cs1 = *(const float4*)&C[VS1 + (c0+1)*4];
    float4 cd0 = *(const float4*)&C[VD1 + c0*4];
    float4 cd1 = *(const float4*)&C[VD1 + (c0+1)*4];
    sh[0] = v0*cs0.x + v1*cs1.x; sh[1] = v0*cs0.y + v1*cs1.y;
    sh[2] = v0*cs0.z + v1*cs1.z; sh[3] = v0*cs0.w + v1*cs1.w;
    dh[0] = v0*cd0.x + v1*cd1.x; dh[1] = v0*cd0.y + v1*cd1.y;
    dh[2] = v0*cd0.z + v1*cd1.z; dh[3] = v0*cd0.w + v1*cd1.w;
  }
  #pragma unroll
  for (int o = 32; o; o >>= 1){
    #pragma unroll
    for (int h = 0; h < 4; ++h){
      sh[h] += __shfl_xor(sh[h], o);
      dh[h] += __shfl_xor(dh[h], o);
    }
  }
  if (lane == 0){
    *(float4*)&ss1[(size_t)n*4] = make_float4(sh[0], sh[1], sh[2], sh[3]);
    *(float4*)&sd1[(size_t)n*4] = make_float4(dh[0], dh[1], dh[2], dh[3]);
  }
}

// ---- edge-parallel alpha (layer 2) ------------------------------------------
__global__ void k_al2(const int4* __restrict__ epk, const float* __restrict__ ss2,
                      const float* __restrict__ sd2, const float* __restrict__ C,
                      float* __restrict__ ex2){
  int p = blockIdx.x * 256 + threadIdx.x;
  if (p >= ET) return;
  int4 pk = epk[p];
  int s = pk.x, d = pk.y;
  float ax = b2f((unsigned)pk.z & 0xffffu), ay = b2f((unsigned)pk.z >> 16);
  float az = b2f((unsigned)pk.w & 0xffffu), aw = b2f((unsigned)pk.w >> 16);
  ex2[p] = __expf(lrelu(ss2[s] + sd2[d] +
             ax*C[VE2] + ay*C[VE2+1] + az*C[VE2+2] + aw*C[VE2+3]));
}

// ---- FUSED two-stage GEMM (round-10 LDS-staged structure) -------------------
// stage1: xt[32][512] = gelu(agg @ W1 + b1); ss2/sd2 accumulated IN REGISTERS
// from epilogue values (no LDS read-back). stage2: xs2 = xt @ W2t^T.
__global__ __launch_bounds__(256) void k_gemm12(
    const unsigned short* __restrict__ agg, const unsigned short* __restrict__ W1t,
    const unsigned short* __restrict__ W2t, const float* __restrict__ b1,
    const float* __restrict__ Cv, unsigned short* __restrict__ xs2b,
    float* __restrict__ ss2, float* __restrict__ sd2){
  __shared__ unsigned short xt[32 * 520];   // 33.3 KB
  __shared__ unsigned short Bs[128 * 40];   // 10.2 KB
  __shared__ unsigned short As[32 * 40];    //  2.6 KB
  __shared__ float ssp[32][2], sdp[32][2];
  int tid = threadIdx.x, lane = tid & 63, w = tid >> 6;
  int wm = w & 1, wn = w >> 1;
  int m15 = lane & 15, rq = lane >> 4;
  int r0 = blockIdx.x * 32;
  int lrow = wm * 16 + m15;
  float s2a = 0.f, s2d = 0.f;
  constexpr size_t HS = (size_t)NN * KP1;
  // ---------------- stage 1 ----------------
  for (int h = 0; h < 4; ++h){
    f4v acc[4] = {};
    const unsigned short* Ah = agg + (size_t)h * HS;
    const unsigned short* Wh = W1t + h * 128 * KP1;
    for (int k0 = 0; k0 < KP1; k0 += 32){
      if (tid < 128){
        int r = tid >> 2, c = tid & 3;
        int gr = r0 + r; if (gr >= NN) gr = NN - 1;
        *(uint4*)&As[r*40 + c*8] = *(const uint4*)&Ah[(size_t)gr*KP1 + k0 + c*8];
      }
      #pragma unroll
      for (int i = 0; i < 2; ++i){
        int idx = tid + i*256;
        int r = idx >> 2, c = idx & 3;
        *(uint4*)&Bs[r*40 + c*8] = *(const uint4*)&Wh[r*KP1 + k0 + c*8];
      }
      __syncthreads();
      s8v af = *(const s8v*)&As[lrow*40 + rq*8];
      #pragma unroll
      for (int ni = 0; ni < 4; ++ni){
        s8v bf = *(const s8v*)&Bs[(wn*64 + ni*16 + m15)*40 + rq*8];
        acc[ni] = __builtin_amdgcn_mfma_f32_16x16x32_bf16(bf, af, acc[ni], 0, 0, 0);
      }
      __syncthreads();
    }
    #pragma unroll
    for (int ni = 0; ni < 4; ++ni){
      int cb = h*128 + wn*64 + ni*16 + rq*4;
      float4 bv = *(const float4*)&b1[cb];
      float v0 = gelu_fast(acc[ni][0] + bv.x);
      float v1 = gelu_fast(acc[ni][1] + bv.y);
      float v2 = gelu_fast(acc[ni][2] + bv.z);
      float v3 = gelu_fast(acc[ni][3] + bv.w);
      float4 cs = *(const float4*)&Cv[VS2 + cb];
      float4 cd = *(const float4*)&Cv[VD2 + cb];
      s2a += v0*cs.x + v1*cs.y + v2*cs.z + v3*cs.w;
      s2d += v0*cd.x + v1*cd.y + v2*cd.z + v3*cd.w;
      *(uint2*)&xt[lrow*520 + cb] = make_uint2(pk2(v0,v1), pk2(v2,v3));
    }
  }
  // ss2/sd2: reduce over rq lanes, then across wn waves via tiny LDS
  s2a += __shfl_xor(s2a, 16); s2a += __shfl_xor(s2a, 32);
  s2d += __shfl_xor(s2d, 16); s2d += __shfl_xor(s2d, 32);
  if (rq == 0){ ssp[lrow][wn] = s2a; sdp[lrow][wn] = s2d; }
  __syncthreads();
  if (tid < 32 && r0 + tid < NN){
    ss2[r0 + tid] = ssp[tid][0] + ssp[tid][1];
    sd2[r0 + tid] = sdp[tid][0] + sdp[tid][1];
  }
  // ---------------- stage 2 ----------------
  f4v acc2[4] = {};
  for (int k0 = 0; k0 < 512; k0 += 32){
    #pragma unroll
    for (int i = 0; i < 2; ++i){
      int idx = tid + i*256;
      int r = idx >> 2, c = idx & 3;
      *(uint4*)&Bs[r*40 + c*8] = *(const uint4*)&W2t[r*512 + k0 + c*8];
    }
    __syncthreads();
    s8v af = *(const s8v*)&xt[lrow*520 + k0 + rq*8];
    #pragma unroll
    for (int ni = 0; ni < 4; ++ni){
      s8v bf = *(const s8v*)&Bs[(wn*64 + ni*16 + m15)*40 + rq*8];
      acc2[ni] = __builtin_amdgcn_mfma_f32_16x16x32_bf16(bf, af, acc2[ni], 0, 0, 0);
    }
    __syncthreads();
  }
  int grow = r0 + lrow;
  if (grow < NN){
    #pragma unroll
    for (int ni = 0; ni < 4; ++ni){
      int gc = wn*64 + ni*16 + rq*4;
      *(uint2*)&xs2b[(size_t)grow*128 + gc] =
          make_uint2(pk2(acc2[ni][0], acc2[ni][1]), pk2(acc2[ni][2], acc2[ni][3]));
    }
  }
}

// ---- layer1 aggregation: wave/node, 2-edge pipelined gather -----------------
__global__ __launch_bounds__(256) void k_aggnf(const int* __restrict__ csr,
    const int4* __restrict__ epk, const float4* __restrict__ exf,
    const unsigned short* __restrict__ nfb, unsigned short* __restrict__ agg){
  int lane = threadIdx.x & 63, w = threadIdx.x >> 6;
  int n = blockIdx.x * 4 + w;
  if (n >= NN) return;
  int off = __builtin_amdgcn_readfirstlane(csr[n]);
  int end = __builtin_amdgcn_readfirstlane(csr[n + 1]);
  int col = lane * 2;
  bool act = lane < 36;
  float d0=0,d1=0,d2=0,d3=0;
  float a00=0,a01=0,a10=0,a11=0,a20=0,a21=0,a30=0,a31=0;
  int p = off;
  for (; p + 2 <= end; p += 2){
    int s0 = epk[p].x, s1 = epk[p+1].x;
    float4 e0 = exf[p], e1 = exf[p+1];
    unsigned u0 = 0, u1 = 0;
    if (act){
      u0 = *(const unsigned*)&nfb[(size_t)s0 * NFP + col];
      u1 = *(const unsigned*)&nfb[(size_t)s1 * NFP + col];
    }
    d0 += e0.x + e1.x; d1 += e0.y + e1.y; d2 += e0.z + e1.z; d3 += e0.w + e1.w;
    float v00 = b2f(u0 & 0xffffu), v01 = b2f(u0 >> 16);
    float v10 = b2f(u1 & 0xffffu), v11 = b2f(u1 >> 16);
    a00 += e0.x*v00 + e1.x*v10; a01 += e0.x*v01 + e1.x*v11;
    a10 += e0.y*v00 + e1.y*v10; a11 += e0.y*v01 + e1.y*v11;
    a20 += e0.z*v00 + e1.z*v10; a21 += e0.z*v01 + e1.z*v11;
    a30 += e0.w*v00 + e1.w*v10; a31 += e0.w*v01 + e1.w*v11;
  }
  if (p < end){
    int s0 = epk[p].x;
    float4 e0 = exf[p];
    unsigned u0 = 0;
    if (act) u0 = *(const unsigned*)&nfb[(size_t)s0 * NFP + col];
    d0 += e0.x; d1 += e0.y; d2 += e0.z; d3 += e0.w;
    float v00 = b2f(u0 & 0xffffu), v01 = b2f(u0 >> 16);
    a00 += e0.x*v00; a01 += e0.x*v01;
    a10 += e0.y*v00; a11 += e0.y*v01;
    a20 += e0.z*v00; a21 += e0.z*v01;
    a30 += e0.w*v00; a31 += e0.w*v01;
  }
  float i0 = 1.f/(d0+1e-16f), i1 = 1.f/(d1+1e-16f);
  float i2 = 1.f/(d2+1e-16f), i3 = 1.f/(d3+1e-16f);
  constexpr size_t HS = (size_t)NN * KP1;
  size_t base = (size_t)n * KP1 + col;
  if (act){
    *(unsigned*)&agg[base]        = pk2(a00*i0, a01*i0);
    *(unsigned*)&agg[base +   HS] = pk2(a10*i1, a11*i1);
    *(unsigned*)&agg[base + 2*HS] = pk2(a20*i2, a21*i2);
    *(unsigned*)&agg[base + 3*HS] = pk2(a30*i3, a31*i3);
  } else if (lane < 48){                // zero cols 72..95
    *(unsigned*)&agg[base]        = 0u;
    *(unsigned*)&agg[base +   HS] = 0u;
    *(unsigned*)&agg[base + 2*HS] = 0u;
    *(unsigned*)&agg[base + 3*HS] = 0u;
  }
}

// ---- layer2 aggregation: 4-edge pipelined gather + GELU + LN + projections --
__global__ __launch_bounds__(256) void k_agg2(
    const int* __restrict__ csr, const int4* __restrict__ epk,
    const float* __restrict__ ex2, const unsigned short* __restrict__ xs2b,
    const float* __restrict__ b2, const float* __restrict__ lng,
    const float* __restrict__ lnb, const float* __restrict__ pw,
    const float* __restrict__ pb, const float* __restrict__ dwm,
    const float* __restrict__ dbv, float* __restrict__ out){
  int lane = threadIdx.x & 63, w = threadIdx.x >> 6;
  int n = blockIdx.x * 4 + w;
  if (n >= NN) return;
  int off = __builtin_amdgcn_readfirstlane(csr[n]);
  int end = __builtin_amdgcn_readfirstlane(csr[n + 1]);
  int c0 = lane * 2;
  float acc0 = 0.f, acc1 = 0.f, den = 0.f;
  int p = off;
  for (; p + 4 <= end; p += 4){
    int s0 = epk[p].x, s1 = epk[p+1].x, s2 = epk[p+2].x, s3 = epk[p+3].x;
    float e0 = ex2[p], e1 = ex2[p+1], e2 = ex2[p+2], e3 = ex2[p+3];
    unsigned u0 = *(const unsigned*)&xs2b[(size_t)s0 * 128 + c0];
    unsigned u1 = *(const unsigned*)&xs2b[(size_t)s1 * 128 + c0];
    unsigned u2 = *(const unsigned*)&xs2b[(size_t)s2 * 128 + c0];
    unsigned u3 = *(const unsigned*)&xs2b[(size_t)s3 * 128 + c0];
    den += (e0 + e1) + (e2 + e3);
    acc0 += e0*b2f(u0 & 0xffffu) + e1*b2f(u1 & 0xffffu)
          + e2*b2f(u2 & 0xffffu) + e3*b2f(u3 & 0xffffu);
    acc1 += e0*b2f(u0 >> 16) + e1*b2f(u1 >> 16)
          + e2*b2f(u2 >> 16) + e3*b2f(u3 >> 16);
  }
  for (; p + 2 <= end; p += 2){
    int s0 = epk[p].x, s1 = epk[p+1].x;
    float e0 = ex2[p], e1 = ex2[p+1];
    unsigned u0 = *(const unsigned*)&xs2b[(size_t)s0 * 128 + c0];
    unsigned u1 = *(const unsigned*)&xs2b[(size_t)s1 * 128 + c0];
    den += e0 + e1;
    acc0 += e0*b2f(u0 & 0xffffu) + e1*b2f(u1 & 0xffffu);
    acc1 += e0*b2f(u0 >> 16) + e1*b2f(u1 >> 16);
  }
  if (p < end){
    int s0 = epk[p].x;
    float e0 = ex2[p];
    unsigned u0 = *(const unsigned*)&xs2b[(size_t)s0 * 128 + c0];
    den += e0;
    acc0 += e0*b2f(u0 & 0xffffu);
    acc1 += e0*b2f(u0 >> 16);
  }
  float invd = 1.f / (den + 1e-16f);
  float g0 = gelu_fast(acc0 * invd + b2[c0]);
  float g1 = gelu_fast(acc1 * invd + b2[c0 + 1]);
  float s = g0 + g1;
  #pragma unroll
  for (int o = 32; o; o >>= 1) s += __shfl_xor(s, o);
  float mu = s * (1.f / 128.f);
  float e0 = g0 - mu, e1 = g1 - mu;
  float q = e0*e0 + e1*e1;
  #pragma unroll
  for (int o = 32; o; o >>= 1) q += __shfl_xor(q, o);
  float rstd = rsqrtf(q * (1.f / 128.f) + 1e-5f);
  float y0 = e0 * rstd * lng[c0] + lnb[c0];
  float y1 = e1 * rstd * lng[c0 + 1] + lnb[c0 + 1];
  float pr[12];
  #pragma unroll
  for (int jj = 0; jj < 8; ++jj) pr[jj] = y0 * pw[c0*8 + jj] + y1 * pw[(c0+1)*8 + jj];
  #pragma unroll
  for (int jj = 0; jj < 4; ++jj) pr[8+jj] = y0 * dwm[c0*4 + jj] + y1 * dwm[(c0+1)*4 + jj];
  #pragma unroll
  for (int o = 32; o; o >>= 1)
    #pragma unroll
    for (int jj = 0; jj < 12; ++jj) pr[jj] += __shfl_xor(pr[jj], o);
  if (lane == 0){
    #pragma unroll
    for (int jj = 0; jj < 8; ++jj) out[(size_t)n*8 + jj] = pr[jj] + pb[jj];
    #pragma unroll
    for (int jj = 0; jj < 4; ++jj) out[(size_t)NN*8 + (size_t)n*4 + jj] = pr[8+jj] + dbv[jj];
  }
}

extern "C" void kernel_launch(void* const* d_in, const int* in_sizes, int n_in,
                              void* d_out, int out_size, void* d_ws, size_t ws_size,
                              hipStream_t stream){
  const float* nf  = (const float*)d_in[0];
  const int*   ei  = (const int*)  d_in[1];
  const float* ea  = (const float*)d_in[2];
  const float* W1  = (const float*)d_in[3];
  const float* as1 = (const float*)d_in[4];
  const float* ad1 = (const float*)d_in[5];
  const float* We1 = (const float*)d_in[6];
  const float* ae1 = (const float*)d_in[7];
  const float* b1  = (const float*)d_in[8];
  const float* W2  = (const float*)d_in[9];
  const float* as2 = (const float*)d_in[10];
  const float* ad2 = (const float*)d_in[11];
  const float* We2 = (const float*)d_in[12];
  const float* ae2 = (const float*)d_in[13];
  const float* b2  = (const float*)d_in[14];
  const float* lng = (const float*)d_in[15];
  const float* lnb = (const float*)d_in[16];
  const float* pw  = (const float*)d_in[17];
  const float* pb  = (const float*)d_in[18];
  const float* dw  = (const float*)d_in[19];
  const float* db  = (const float*)d_in[20];
  float* out = (float*)d_out;

  float* wf = (float*)d_ws;
  int*      cnt  = (int*)     (wf + CNT_O);
  int*      csr  = (int*)     (wf + CSR_O);
  int*      bsum = (int*)     (wf + BSUM_O);
  int*      boff = (int*)     (wf + BOFF_O);
  int4*     epk  = (int4*)    (wf + EPK_O);
  float4*   exf1 = (float4*)  (wf + EXF1_O);
  float*    ex2  =            (wf + EXF2_O);
  float*    ss1  =            (wf + SS1_O);
  float*    sd1  =            (wf + SD1_O);
  float*    ss2  =            (wf + SS2_O);
  float*    sd2  =            (wf + SD2_O);
  float*    Cc   =            (wf + CST_O);
  unsigned short* W1t = (unsigned short*)(wf + W1T_O);
  unsigned short* W2t = (unsigned short*)(wf + W2T_O);
  unsigned short* nfb = (unsigned short*)(wf + NFB_O);
  unsigned short* agg = (unsigned short*)(wf + AGG_O);
  unsigned short* xs2b= (unsigned short*)(wf + XS2_O);

  hipMemsetAsync(cnt, 0, NN * sizeof(int), stream);
  k_prep<<<1, 512, 0, stream>>>(W1, as1, ad1, We1, ae1, W2, as2, ad2, We2, ae2, Cc);
  k_tw<<<(4*128*KP1 + 128*512 + 255) / 256, 256, 0, stream>>>(W1, W2, W1t, W2t);
  k_cnfs1<<<(NN + 3) / 4, 256, 0, stream>>>(nf, Cc, nfb, ss1, sd1);
  k_deg<<<(NE + 255) / 256, 256, 0, stream>>>(ei, cnt);
  k_scan1<<<SCB, 256, 0, stream>>>(cnt, bsum);
  k_scan2<<<1, 256, 0, stream>>>(bsum, boff);
  k_scan3<<<SCB, 256, 0, stream>>>(cnt, boff, csr);
  k_fill<<<(NE + 255) / 256, 256, 0, stream>>>(ei, ea, csr, cnt, epk, ss1, sd1, Cc, exf1);
  k_loopself<<<(NN + 255) / 256, 256, 0, stream>>>(csr, epk, ss1, sd1, Cc, exf1);
  k_aggnf<<<(NN + 3) / 4, 256, 0, stream>>>(csr, epk, exf1, nfb, agg);
  k_gemm12<<<(NN + 31) / 32, 256, 0, stream>>>(agg, W1t, W2t, b1, Cc, xs2b, ss2, sd2);
  k_al2<<<(ET + 255) / 256, 256, 0, stream>>>(epk, ss2, sd2, Cc, ex2);
  k_agg2<<<(NN + 3) / 4, 256, 0, stream>>>(csr, epk, ex2, xs2b,
                                           b2, lng, lnb, pw, pb, dw, db, out);
}